// Round 9
// baseline (119.486 us; speedup 1.0000x reference)
//
#include <hip/hip_runtime.h>
#include <hip/hip_bf16.h>

// Problem constants
#define DD 512
#define HIDN 64
#define NTREE 64
#define NIN 7           // internal nodes
#define PPTC 3607       // NI*D + NI + NL*2
#define TOTP 230912     // PPT*T + T
#define SWROWS 448      // T*NI

typedef __attribute__((ext_vector_type(8))) short bf16x8;
typedef __attribute__((ext_vector_type(4))) float f32x4;
typedef __attribute__((ext_vector_type(8))) _Float16 h16x8;

__device__ __forceinline__ unsigned short f2bf(float f) {
  unsigned u = __float_as_uint(f);
  unsigned r = (u + 0x7FFFu + ((u >> 16) & 1u)) >> 16;   // RNE
  return (unsigned short)r;
}
__device__ __forceinline__ float sigmoidf_(float x) {
  return 1.0f / (1.0f + __expf(-x));
}
__device__ __forceinline__ uint2 pack_bf16x4(float4 v) {
  uint2 pk;
  pk.x = (unsigned)f2bf(v.x) | ((unsigned)f2bf(v.y) << 16);
  pk.y = (unsigned)f2bf(v.z) | ((unsigned)f2bf(v.w) << 16);
  return pk;
}
// 8 fp32 -> bf16x8 via HW packed convert (RNE)
__device__ __forceinline__ bf16x8 cvt8(float4 a, float4 b) {
  unsigned u0, u1, u2, u3;
  asm("v_cvt_pk_bf16_f32 %0, %1, %2" : "=v"(u0) : "v"(a.x), "v"(a.y));
  asm("v_cvt_pk_bf16_f32 %0, %1, %2" : "=v"(u1) : "v"(a.z), "v"(a.w));
  asm("v_cvt_pk_bf16_f32 %0, %1, %2" : "=v"(u2) : "v"(b.x), "v"(b.y));
  asm("v_cvt_pk_bf16_f32 %0, %1, %2" : "=v"(u3) : "v"(b.z), "v"(b.w));
  union { unsigned u[4]; bf16x8 v; } r;
  r.u[0] = u0; r.u[1] = u1; r.u[2] = u2; r.u[3] = u3;
  return r.v;
}
// async global->LDS, 16B per lane
__device__ __forceinline__ void gl_lds16(const void* g, void* l) {
  __builtin_amdgcn_global_load_lds(
      (const __attribute__((address_space(1))) unsigned int*)g,
      (__attribute__((address_space(3))) unsigned int*)l, 16, 0, 0);
}

// ---------------------------------------------------------------------------
// Kernel 1: train path. 256 blocks x 256 thr (4 waves), 32 rows/block.
// (unchanged — known-good)
// ---------------------------------------------------------------------------
__global__ __launch_bounds__(256) void k_train(
    const float* __restrict__ Xtr, const float* __restrict__ W1,
    const float* __restrict__ b1, const float* __restrict__ g1,
    const float* __restrict__ be1, const float* __restrict__ W2,
    const float* __restrict__ b2, float* __restrict__ c_part)
{
  __shared__ __align__(16) char smem[37888];
  char* Xc  = smem;
  char* W1c = smem + 8192;
  char* Hl  = smem + 24576;
  char* W2l = smem + 28672;
  float* lnb = (float*)(smem + 36864);
  float* cp  = (float*)(smem + 37376);

  const int tid = threadIdx.x;
  const int lane = tid & 63;
  const int wv = tid >> 6;
  const int l15 = lane & 15;
  const int gq = lane >> 4;
  const int wm = wv >> 1;
  const int wn = wv & 1;
  const int rb0 = blockIdx.x * 32;

  const float4* X4g = (const float4*)Xtr;
  const float4* W4g = (const float4*)W1;

#pragma unroll
  for (int s = 0; s < 4; ++s) {
    int fidx = tid + s * 256;
    int n = fidx >> 4, kq = fidx & 15;
    float4 v = ((const float4*)W2)[n * 16 + kq];
    uint2 pk = pack_bf16x4(v);
    int off = n * 128 + kq * 8; off ^= (n & 7) << 4;
    *(uint2*)(W2l + off) = pk;
  }

  int xga[4], xo[4];
#pragma unroll
  for (int s = 0; s < 4; ++s) {
    int f = tid + s * 256;
    int m = f >> 5, kq = f & 31;
    xga[s] = (rb0 + m) * 128 + kq;
    xo[s] = (m * 256 + kq * 8) ^ ((m & 7) << 4);
  }
  int wga[8], wo[8];
#pragma unroll
  for (int s = 0; s < 8; ++s) {
    int f = tid + s * 256;
    int n = f >> 5, kq = f & 31;
    wga[s] = n * 128 + kq;
    wo[s] = (n * 256 + kq * 8) ^ ((n & 7) << 4);
  }

  f32x4 acc1[2];
#pragma unroll
  for (int nt = 0; nt < 2; ++nt) { f32x4 z = {0.f,0.f,0.f,0.f}; acc1[nt] = z; }

  float4 xr[4], wr[8];
#pragma unroll
  for (int s = 0; s < 4; ++s) xr[s] = X4g[xga[s]];
#pragma unroll
  for (int s = 0; s < 8; ++s) wr[s] = W4g[wga[s]];

  for (int kc = 0; kc < 4; ++kc) {
    __syncthreads();
#pragma unroll
    for (int s = 0; s < 4; ++s) *(uint2*)(Xc + xo[s]) = pack_bf16x4(xr[s]);
#pragma unroll
    for (int s = 0; s < 8; ++s) *(uint2*)(W1c + wo[s]) = pack_bf16x4(wr[s]);
    if (kc < 3) {
      int ko = (kc + 1) * 32;
#pragma unroll
      for (int s = 0; s < 4; ++s) xr[s] = X4g[xga[s] + ko];
#pragma unroll
      for (int s = 0; s < 8; ++s) wr[s] = W4g[wga[s] + ko];
    }
    __syncthreads();
#pragma unroll
    for (int ks = 0; ks < 4; ++ks) {
      int arow = wm * 16 + l15;
      int aoff = (arow * 256 + ks * 64 + gq * 16) ^ ((arow & 7) << 4);
      bf16x8 afr = *(const bf16x8*)(Xc + aoff);
#pragma unroll
      for (int nt = 0; nt < 2; ++nt) {
        int brow = wn * 32 + nt * 16 + l15;
        int boff = (brow * 256 + ks * 64 + gq * 16) ^ ((brow & 7) << 4);
        bf16x8 bfr = *(const bf16x8*)(W1c + boff);
        acc1[nt] = __builtin_amdgcn_mfma_f32_16x16x32_bf16(afr, bfr, acc1[nt], 0, 0, 0);
      }
    }
  }

  float b1v[2], g1v[2], be1v[2], b2v[2];
#pragma unroll
  for (int nt = 0; nt < 2; ++nt) {
    int c = wn * 32 + nt * 16 + l15;
    b1v[nt] = b1[c]; g1v[nt] = g1[c]; be1v[nt] = be1[c]; b2v[nt] = b2[c];
  }
  float yv[2][4], s_[4], q_[4];
#pragma unroll
  for (int i = 0; i < 4; ++i) {
    float s = 0.f, q = 0.f;
#pragma unroll
    for (int nt = 0; nt < 2; ++nt) {
      float y = acc1[nt][i] + b1v[nt];
      yv[nt][i] = y; s += y; q += y * y;
    }
    s_[i] = s; q_[i] = q;
  }
#pragma unroll
  for (int off = 1; off < 16; off <<= 1) {
#pragma unroll
    for (int i = 0; i < 4; ++i) {
      s_[i] += __shfl_xor(s_[i], off);
      q_[i] += __shfl_xor(q_[i], off);
    }
  }
  if (l15 == 0) {
#pragma unroll
    for (int i = 0; i < 4; ++i) {
      int row = wm * 16 + gq * 4 + i;
      float2 sv; sv.x = s_[i]; sv.y = q_[i];
      *(float2*)(lnb + (row * 2 + wn) * 2) = sv;
    }
  }
  __syncthreads();
#pragma unroll
  for (int i = 0; i < 4; ++i) {
    int row = wm * 16 + gq * 4 + i;
    float2 e0 = *(float2*)(lnb + (row * 2 + 0) * 2);
    float2 e1 = *(float2*)(lnb + (row * 2 + 1) * 2);
    float m = (e0.x + e1.x) * (1.0f / 64.0f);
    float var = (e0.y + e1.y) * (1.0f / 64.0f) - m * m;
    float rstd = rsqrtf(var + 1e-5f);
#pragma unroll
    for (int nt = 0; nt < 2; ++nt) {
      float h = (yv[nt][i] - m) * rstd * g1v[nt] + be1v[nt];
      h = fmaxf(h, 0.0f);
      int col = wn * 32 + nt * 16 + l15;
      int off2 = (row * 128 + col * 2) ^ ((row & 7) << 4);
      *(unsigned short*)(Hl + off2) = f2bf(h);
    }
  }
  __syncthreads();

  f32x4 acc2[2];
#pragma unroll
  for (int nt = 0; nt < 2; ++nt) { f32x4 z = {0.f,0.f,0.f,0.f}; acc2[nt] = z; }
#pragma unroll
  for (int ks = 0; ks < 2; ++ks) {
    int arow = wm * 16 + l15;
    int aoff = (arow * 128 + ks * 64 + gq * 16) ^ ((arow & 7) << 4);
    bf16x8 afr = *(const bf16x8*)(Hl + aoff);
#pragma unroll
    for (int nt = 0; nt < 2; ++nt) {
      int brow = wn * 32 + nt * 16 + l15;
      int boff = (brow * 128 + ks * 64 + gq * 16) ^ ((brow & 7) << 4);
      bf16x8 bfr = *(const bf16x8*)(W2l + boff);
      acc2[nt] = __builtin_amdgcn_mfma_f32_16x16x32_bf16(afr, bfr, acc2[nt], 0, 0, 0);
    }
  }
  float cs[2];
#pragma unroll
  for (int nt = 0; nt < 2; ++nt) {
    float s = 0.f;
#pragma unroll
    for (int i = 0; i < 4; ++i) s += fmaxf(acc2[nt][i] + b2v[nt], 0.0f);
    cs[nt] = s;
  }
#pragma unroll
  for (int nt = 0; nt < 2; ++nt) {
    cs[nt] += __shfl_xor(cs[nt], 16);
    cs[nt] += __shfl_xor(cs[nt], 32);
  }
  if (lane < 16) {
#pragma unroll
    for (int nt = 0; nt < 2; ++nt)
      cp[wm * 64 + wn * 32 + nt * 16 + lane] = cs[nt];
  }
  __syncthreads();
  if (tid < 64) c_part[blockIdx.x * 64 + tid] = cp[tid] + cp[64 + tid];
}

// ---------------------------------------------------------------------------
// Kernel 2: reduce c partials + head MLP. 1 block x 256 threads. (unchanged)
// ---------------------------------------------------------------------------
__global__ __launch_bounds__(256) void k_head(
    const float* __restrict__ c_part,
    const float* __restrict__ H1, const float* __restrict__ hb1,
    const float* __restrict__ g2, const float* __restrict__ be2,
    const float* __restrict__ H2, const float* __restrict__ hb2,
    float* __restrict__ u2out)
{
  __shared__ float part[256];
  __shared__ float clds[64];
  __shared__ float u1lds[128];
  __shared__ float red[8];
  int tid = threadIdx.x;
  {
    int col = tid & 63, g = tid >> 6;
    float s0 = 0.f, s1 = 0.f, s2 = 0.f, s3 = 0.f;
    int b0 = g * 64;
    for (int b = 0; b < 64; b += 4) {
      s0 += c_part[(b0 + b + 0) * 64 + col];
      s1 += c_part[(b0 + b + 1) * 64 + col];
      s2 += c_part[(b0 + b + 2) * 64 + col];
      s3 += c_part[(b0 + b + 3) * 64 + col];
    }
    part[tid] = (s0 + s1) + (s2 + s3);
  }
  __syncthreads();
  if (tid < 64)
    clds[tid] = (part[tid] + part[64 + tid] + part[128 + tid] + part[192 + tid]) * (1.0f / 8192.0f);
  __syncthreads();
  float acc = 0.f;
  if (tid < 128) {
    float a0 = 0.f, a1 = 0.f, a2 = 0.f, a3 = 0.f;
    for (int k = 0; k < 64; k += 4) {
      a0 += clds[k + 0] * H1[tid * 64 + k + 0];
      a1 += clds[k + 1] * H1[tid * 64 + k + 1];
      a2 += clds[k + 2] * H1[tid * 64 + k + 2];
      a3 += clds[k + 3] * H1[tid * 64 + k + 3];
    }
    acc = hb1[tid] + ((a0 + a1) + (a2 + a3));
  }
  float s = acc, q = acc * acc;
#pragma unroll
  for (int off = 1; off < 64; off <<= 1) { s += __shfl_xor(s, off); q += __shfl_xor(q, off); }
  int wv = tid >> 6;
  if ((tid & 63) == 0) { red[wv * 2] = s; red[wv * 2 + 1] = q; }
  __syncthreads();
  float S = red[0] + red[2], Q = red[1] + red[3];
  float m = S * (1.0f / 128.0f);
  float var = Q * (1.0f / 128.0f) - m * m;
  float rstd = rsqrtf(var + 1e-5f);
  if (tid < 128)
    u1lds[tid] = fmaxf((acc - m) * rstd * g2[tid] + be2[tid], 0.0f);
  __syncthreads();
  if (tid < 128) {
    float c0 = 0.f, c1 = 0.f, c2 = 0.f, c3 = 0.f;
    for (int k = 0; k < 128; k += 4) {
      c0 += u1lds[k + 0] * H2[tid * 128 + k + 0];
      c1 += u1lds[k + 1] * H2[tid * 128 + k + 1];
      c2 += u1lds[k + 2] * H2[tid * 128 + k + 2];
      c3 += u1lds[k + 3] * H2[tid * 128 + k + 3];
    }
    u2out[tid] = fmaxf(hb2[tid] + ((c0 + c1) + (c2 + c3)), 0.0f);
  }
}

// ---------------------------------------------------------------------------
// Kernel 3: params = u2 @ H3^T + hb3, routed to Bfrag / sb / ll / tw.
// (r7 version) Bfrag (u16 idx): kt*16384 + col*32 + (gq ^ (col&3))*8 + j
// ---------------------------------------------------------------------------
__global__ __launch_bounds__(256) void k_params(
    const float* __restrict__ H3, const float* __restrict__ hb3,
    const float* __restrict__ u2,
    unsigned short* __restrict__ Bfrag, float* __restrict__ sb,
    float* __restrict__ ll, float* __restrict__ tw)
{
  __shared__ float u2l[128];
  int tid = threadIdx.x;
  if (tid < 128) u2l[tid] = u2[tid];
  __syncthreads();
  int row = blockIdx.x * 64 + (tid >> 2);
  int sub = tid & 3;
  float acc = 0.0f;
  const float4* H4 = (const float4*)H3;
#pragma unroll
  for (int j = 0; j < 8; ++j) {
    int f = j * 4 + sub;
    float4 v = H4[row * 32 + f];
    acc += v.x * u2l[f * 4] + v.y * u2l[f * 4 + 1] + v.z * u2l[f * 4 + 2] + v.w * u2l[f * 4 + 3];
  }
  acc += __shfl_xor(acc, 1);
  acc += __shfl_xor(acc, 2);
  if (sub == 0) {
    float val = acc + hb3[row];
    if (row >= 230848) {
      tw[row - 230848] = val;
    } else {
      int t = row / PPTC;
      int r = row - t * PPTC;
      if (r < 3584) {
        int n = r >> 9, d = r & 511;
        int col = t * 7 + n;
        int kt = d >> 5, gq = (d >> 3) & 3, j = d & 7;
        Bfrag[kt * 16384 + col * 32 + (gq ^ (col & 3)) * 8 + j] = f2bf(val);
      } else if (r < 3591) {
        sb[t * 7 + (r - 3584)] = val;
      } else {
        ll[t * 16 + (r - 3591)] = val;
      }
    }
  }
}

// ---------------------------------------------------------------------------
// Kernel 4: main inference — r7 structure, MEASUREMENT CONFIG: grid 512 with
// mblk = blockIdx.x & 255, i.e. every M-tile computed by TWO duplicate blocks
// writing identical values (plain stores, idempotent, deterministic). This
// doubles the dispatch duration so it rises above the 66 µs harness fills
// into rocprof's top-5 WITH counters. kt = dur/2.
// ---------------------------------------------------------------------------
__global__ __launch_bounds__(512) void k_test(
    const float* __restrict__ Xt, const unsigned short* __restrict__ Bfrag,
    const float* __restrict__ sb, const float* __restrict__ ll,
    const float* __restrict__ tw, float* __restrict__ out)
{
  // ring: 3 x (X 16384 + B 32768) = 147456 ; qlds 4096 ; sbl 1792 ; outl 1024
  __shared__ __align__(16) char smem[154368];
  char* Pl = smem;                           // tree-phase alias (32 KB)
  float* qlds = (float*)(smem + 147456);
  float* sbl  = (float*)(smem + 151552);
  float* outl = (float*)(smem + 153344);

  const int tid = threadIdx.x;
  const int lane = tid & 63;
  const int wv = tid >> 6;
  const int l15 = lane & 15;
  const int gq = lane >> 4;
  const int wm = wv >> 2;
  const int wn = wv & 3;
  const int bm0 = (blockIdx.x & 255) * 128;

  const float4* X4 = (const float4*)Xt;
  const char* Bf = (const char*)Bfrag;

  // ---- prologue scalars: sb -> LDS, fused qprep (wave 0) ----
  if (tid < 448) sbl[tid] = sb[tid];
  if (tid < 64) {
    int t = tid;
    float x = tw[t];
    float m = x;
#pragma unroll
    for (int off = 1; off < 64; off <<= 1) m = fmaxf(m, __shfl_xor(m, off));
    float e = __expf(x - m);
    float s = e;
#pragma unroll
    for (int off = 1; off < 64; off <<= 1) s += __shfl_xor(s, off);
    float w = e / s;
#pragma unroll
    for (int l = 0; l < 8; ++l) {
      float a = ll[t * 16 + l * 2], b = ll[t * 16 + l * 2 + 1];
      float mm = fmaxf(a, b);
      float e0 = __expf(a - mm), e1 = __expf(b - mm);
      float inv = 2.0f * w / (e0 + e1);
      qlds[t * 16 + l * 2] = e0 * inv;
      qlds[t * 16 + l * 2 + 1] = e1 * inv;
    }
  }

  // X staging: slot s in {tid, tid+512}; row = s>>3, p_lds = s&7,
  // global granule pg = p_lds ^ (row&7)  (pre-swizzled source).
  const int xrow0 = tid >> 3;                  // 0..63
  const int xpg   = (tid & 7) ^ (xrow0 & 7);   // same for slot+512 (row+64)
  const int xsrc0 = (bm0 + xrow0) * 128 + xpg;        // + kt*8 (float4 idx)
  const int xsrc1 = (bm0 + xrow0 + 64) * 128 + xpg;

#define ISSUE_TILE(t_) do { \
    char* xb_ = smem + ((t_) % 3) * 49152; \
    char* bb_ = xb_ + 16384; \
    gl_lds16(X4 + (xsrc0 + (t_) * 8), xb_ + tid * 16); \
    gl_lds16(X4 + (xsrc1 + (t_) * 8), xb_ + (tid + 512) * 16); \
    const char* bt_ = Bf + (t_) * 32768; \
    gl_lds16(bt_ + tid * 16,          bb_ + tid * 16); \
    gl_lds16(bt_ + (tid + 512) * 16,  bb_ + (tid + 512) * 16); \
    gl_lds16(bt_ + (tid + 1024) * 16, bb_ + (tid + 1024) * 16); \
    gl_lds16(bt_ + (tid + 1536) * 16, bb_ + (tid + 1536) * 16); \
  } while (0)

  f32x4 acc[4][7];
#pragma unroll
  for (int mt = 0; mt < 4; ++mt)
#pragma unroll
    for (int nt = 0; nt < 7; ++nt) { f32x4 z = {0.f,0.f,0.f,0.f}; acc[mt][nt] = z; }

  // frag-read offset precompute
  const int xoff0 = (((gq * 2) ^ (l15 & 7)) << 4);       // A float4 #0
  const int xoff1 = (((gq * 2 + 1) ^ (l15 & 7)) << 4);   // A float4 #1
  int arow[4];
#pragma unroll
  for (int mt = 0; mt < 4; ++mt) arow[mt] = (wm * 64 + mt * 16 + l15) * 128;
  const int bxor = ((gq ^ (l15 & 3)) << 4);
  int boffs[7];
#pragma unroll
  for (int nt = 0; nt < 7; ++nt) boffs[nt] = (wn * 112 + nt * 16 + l15) * 64 + bxor;

#define COMPUTE_TILE(t_) do { \
    char* xb_ = smem + ((t_) % 3) * 49152; \
    char* bb_ = xb_ + 16384; \
    bf16x8 abf[4]; \
    _Pragma("unroll") \
    for (int mt = 0; mt < 4; ++mt) { \
      float4 a0 = *(const float4*)(xb_ + arow[mt] + xoff0); \
      float4 a1 = *(const float4*)(xb_ + arow[mt] + xoff1); \
      abf[mt] = cvt8(a0, a1); \
    } \
    _Pragma("unroll") \
    for (int nt = 0; nt < 7; ++nt) { \
      bf16x8 bfr = *(const bf16x8*)(bb_ + boffs[nt]); \
      _Pragma("unroll") \
      for (int mt = 0; mt < 4; ++mt) \
        acc[mt][nt] = __builtin_amdgcn_mfma_f32_16x16x32_bf16(abf[mt], bfr, acc[mt][nt], 0, 0, 0); \
    } } while (0)

  // prologue: 3 tiles in flight (18 loads/thread)
  ISSUE_TILE(0);
  ISSUE_TILE(1);
  ISSUE_TILE(2);
  asm volatile("s_waitcnt lgkmcnt(0)" ::: "memory");   // qlds/sbl ds_writes done

  for (int t = 0; t < 13; ++t) {
    asm volatile("s_waitcnt vmcnt(12)" ::: "memory");   // tile t landed; t+1,t+2 in flight
    __builtin_amdgcn_sched_barrier(0);
    __builtin_amdgcn_s_barrier();
    COMPUTE_TILE(t);
    __builtin_amdgcn_s_barrier();                        // all reads of buf[t%3] done
    ISSUE_TILE(t + 3);
  }
  // t = 13
  asm volatile("s_waitcnt vmcnt(12)" ::: "memory");
  __builtin_amdgcn_sched_barrier(0);
  __builtin_amdgcn_s_barrier();
  COMPUTE_TILE(13);
  __builtin_amdgcn_s_barrier();
  // t = 14
  asm volatile("s_waitcnt vmcnt(6)" ::: "memory");
  __builtin_amdgcn_sched_barrier(0);
  __builtin_amdgcn_s_barrier();
  COMPUTE_TILE(14);
  __builtin_amdgcn_s_barrier();
  // t = 15
  asm volatile("s_waitcnt vmcnt(0)" ::: "memory");
  __builtin_amdgcn_sched_barrier(0);
  __builtin_amdgcn_s_barrier();
  COMPUTE_TILE(15);
  __syncthreads();   // full drain before tree phase aliases the ring

  // q into registers (tree t = lane)
  float qreg[16];
  {
    const float4* q4 = (const float4*)qlds;
#pragma unroll
    for (int j = 0; j < 4; ++j) {
      float4 v = q4[lane * 4 + j];
      qreg[j * 4] = v.x; qreg[j * 4 + 1] = v.y; qreg[j * 4 + 2] = v.z; qreg[j * 4 + 3] = v.w;
    }
  }

  // ---- fused sigmoid + soft-tree + mixing, 4 passes of 32 rows ----
#pragma unroll
  for (int rg = 0; rg < 4; ++rg) {
    if (wm == (rg >> 1)) {
#pragma unroll
      for (int mtl = 0; mtl < 2; ++mtl) {
        const int mt = (rg & 1) * 2 + mtl;
#pragma unroll
        for (int nt = 0; nt < 7; ++nt) {
          int col = wn * 112 + nt * 16 + l15;
          float sbv = sbl[col];
          int t = col / 7;
          int j = col - t * 7;
          int slot2 = (t * 8 + j) * 2;
#pragma unroll
          for (int i = 0; i < 4; ++i) {
            int rl = mtl * 16 + gq * 4 + i;
            float p = sigmoidf_(acc[mt][nt][i] + sbv);
            *(_Float16*)(Pl + rl * 1024 + slot2) = (_Float16)p;
          }
        }
      }
    }
    __syncthreads();
#pragma unroll
    for (int k = 0; k < 4; ++k) {
      int rl = wv * 4 + k;
      h16x8 v = *(const h16x8*)(Pl + rl * 1024 + lane * 16);
      float p0 = (float)v[0], p1 = (float)v[1], p2 = (float)v[2];
      float p3 = (float)v[3], p4 = (float)v[4], p5 = (float)v[5], p6 = (float)v[6];
      float n0 = 1.f - p0, n1 = 1.f - p1, n2 = 1.f - p2;
      float a00 = n0 * n1, a01 = n0 * p1, a10 = p0 * n2, a11 = p0 * p2;
      float L0 = a00 * (1.f - p3), L1 = a00 * p3;
      float L2 = a01 * (1.f - p4), L3 = a01 * p4;
      float L4 = a10 * (1.f - p5), L5 = a10 * p5;
      float L6 = a11 * (1.f - p6), L7 = a11 * p6;
      float o0 = L0*qreg[0] + L1*qreg[2] + L2*qreg[4] + L3*qreg[6]
               + L4*qreg[8] + L5*qreg[10] + L6*qreg[12] + L7*qreg[14];
      float o1 = L0*qreg[1] + L1*qreg[3] + L2*qreg[5] + L3*qreg[7]
               + L4*qreg[9] + L5*qreg[11] + L6*qreg[13] + L7*qreg[15];
#pragma unroll
      for (int off = 1; off < 64; off <<= 1) {
        o0 += __shfl_xor(o0, off);
        o1 += __shfl_xor(o1, off);
      }
      if (lane == 0) {
        int gr = rg * 32 + rl;
        outl[gr * 2] = o0;
        outl[gr * 2 + 1] = o1;
      }
    }
    __syncthreads();
  }
  if (tid < 256) out[bm0 * 2 + tid] = outl[tid];
#undef ISSUE_TILE
#undef COMPUTE_TILE
}

// ---------------------------------------------------------------------------
extern "C" void kernel_launch(void* const* d_in, const int* in_sizes, int n_in,
                              void* d_out, int out_size, void* d_ws, size_t ws_size,
                              hipStream_t stream)
{
  const float* Xtr = (const float*)d_in[0];
  const float* Xte = (const float*)d_in[1];
  const float* W1  = (const float*)d_in[3];
  const float* b1  = (const float*)d_in[4];
  const float* g1  = (const float*)d_in[5];
  const float* be1 = (const float*)d_in[6];
  const float* W2  = (const float*)d_in[7];
  const float* b2  = (const float*)d_in[8];
  const float* H1  = (const float*)d_in[9];
  const float* hb1 = (const float*)d_in[10];
  const float* g2  = (const float*)d_in[11];
  const float* be2 = (const float*)d_in[12];
  const float* H2  = (const float*)d_in[13];
  const float* hb2 = (const float*)d_in[14];
  const float* H3  = (const float*)d_in[15];
  const float* hb3 = (const float*)d_in[16];
  float* out = (float*)d_out;
  char* ws = (char*)d_ws;

  float* c_part = (float*)ws;                  // 256*64 f32 = 65536 B
  float* u2     = (float*)(ws + 65536);        // 128 f32
  float* sb     = (float*)(ws + 66048);        // 448 f32
  float* ll     = (float*)(ws + 67840);        // 1024 f32
  float* tw     = (float*)(ws + 71936);        // 64 f32
  unsigned short* Bfrag = (unsigned short*)(ws + 72192); // 16 tiles x 32 KB = 524288 B

  k_train<<<256, 256, 0, stream>>>(Xtr, W1, b1, g1, be1, W2, b2, c_part);
  k_head<<<1, 256, 0, stream>>>(c_part, H1, hb1, g2, be2, H2, hb2, u2);
  k_params<<<3608, 256, 0, stream>>>(H3, hb3, u2, Bfrag, sb, ll, tw);
  k_test<<<512, 512, 0, stream>>>(Xte, Bfrag, sb, ll, tw, out);
}

// Round 10
// 81.225 us; speedup vs baseline: 1.4710x; 1.4710x over previous
//
#include <hip/hip_runtime.h>
#include <hip/hip_bf16.h>

// Problem constants
#define DD 512
#define HIDN 64
#define NTREE 64
#define NIN 7           // internal nodes
#define PPTC 3607       // NI*D + NI + NL*2
#define TOTP 230912     // PPT*T + T
#define SWROWS 448      // T*NI

typedef __attribute__((ext_vector_type(8))) short bf16x8;
typedef __attribute__((ext_vector_type(4))) float f32x4;
typedef __attribute__((ext_vector_type(8))) _Float16 h16x8;

__device__ __forceinline__ unsigned short f2bf(float f) {
  unsigned u = __float_as_uint(f);
  unsigned r = (u + 0x7FFFu + ((u >> 16) & 1u)) >> 16;   // RNE
  return (unsigned short)r;
}
__device__ __forceinline__ float sigmoidf_(float x) {
  return 1.0f / (1.0f + __expf(-x));
}
__device__ __forceinline__ uint2 pack_bf16x4(float4 v) {
  uint2 pk;
  pk.x = (unsigned)f2bf(v.x) | ((unsigned)f2bf(v.y) << 16);
  pk.y = (unsigned)f2bf(v.z) | ((unsigned)f2bf(v.w) << 16);
  return pk;
}
// 4 fp32 -> 4 bf16 (8 B) via HW packed convert (RNE)
__device__ __forceinline__ uint2 cvtpk2(float4 a) {
  unsigned u0, u1;
  asm("v_cvt_pk_bf16_f32 %0, %1, %2" : "=v"(u0) : "v"(a.x), "v"(a.y));
  asm("v_cvt_pk_bf16_f32 %0, %1, %2" : "=v"(u1) : "v"(a.z), "v"(a.w));
  uint2 r; r.x = u0; r.y = u1;
  return r;
}
// async global->LDS, 16B per lane
__device__ __forceinline__ void gl_lds16(const void* g, void* l) {
  __builtin_amdgcn_global_load_lds(
      (const __attribute__((address_space(1))) unsigned int*)g,
      (__attribute__((address_space(3))) unsigned int*)l, 16, 0, 0);
}

// ---------------------------------------------------------------------------
// Kernel 1: train path. 256 blocks x 256 thr (4 waves), 32 rows/block.
// (unchanged — known-good)
// ---------------------------------------------------------------------------
__global__ __launch_bounds__(256) void k_train(
    const float* __restrict__ Xtr, const float* __restrict__ W1,
    const float* __restrict__ b1, const float* __restrict__ g1,
    const float* __restrict__ be1, const float* __restrict__ W2,
    const float* __restrict__ b2, float* __restrict__ c_part)
{
  __shared__ __align__(16) char smem[37888];
  char* Xc  = smem;
  char* W1c = smem + 8192;
  char* Hl  = smem + 24576;
  char* W2l = smem + 28672;
  float* lnb = (float*)(smem + 36864);
  float* cp  = (float*)(smem + 37376);

  const int tid = threadIdx.x;
  const int lane = tid & 63;
  const int wv = tid >> 6;
  const int l15 = lane & 15;
  const int gq = lane >> 4;
  const int wm = wv >> 1;
  const int wn = wv & 1;
  const int rb0 = blockIdx.x * 32;

  const float4* X4g = (const float4*)Xtr;
  const float4* W4g = (const float4*)W1;

#pragma unroll
  for (int s = 0; s < 4; ++s) {
    int fidx = tid + s * 256;
    int n = fidx >> 4, kq = fidx & 15;
    float4 v = ((const float4*)W2)[n * 16 + kq];
    uint2 pk = pack_bf16x4(v);
    int off = n * 128 + kq * 8; off ^= (n & 7) << 4;
    *(uint2*)(W2l + off) = pk;
  }

  int xga[4], xo[4];
#pragma unroll
  for (int s = 0; s < 4; ++s) {
    int f = tid + s * 256;
    int m = f >> 5, kq = f & 31;
    xga[s] = (rb0 + m) * 128 + kq;
    xo[s] = (m * 256 + kq * 8) ^ ((m & 7) << 4);
  }
  int wga[8], wo[8];
#pragma unroll
  for (int s = 0; s < 8; ++s) {
    int f = tid + s * 256;
    int n = f >> 5, kq = f & 31;
    wga[s] = n * 128 + kq;
    wo[s] = (n * 256 + kq * 8) ^ ((n & 7) << 4);
  }

  f32x4 acc1[2];
#pragma unroll
  for (int nt = 0; nt < 2; ++nt) { f32x4 z = {0.f,0.f,0.f,0.f}; acc1[nt] = z; }

  float4 xr[4], wr[8];
#pragma unroll
  for (int s = 0; s < 4; ++s) xr[s] = X4g[xga[s]];
#pragma unroll
  for (int s = 0; s < 8; ++s) wr[s] = W4g[wga[s]];

  for (int kc = 0; kc < 4; ++kc) {
    __syncthreads();
#pragma unroll
    for (int s = 0; s < 4; ++s) *(uint2*)(Xc + xo[s]) = pack_bf16x4(xr[s]);
#pragma unroll
    for (int s = 0; s < 8; ++s) *(uint2*)(W1c + wo[s]) = pack_bf16x4(wr[s]);
    if (kc < 3) {
      int ko = (kc + 1) * 32;
#pragma unroll
      for (int s = 0; s < 4; ++s) xr[s] = X4g[xga[s] + ko];
#pragma unroll
      for (int s = 0; s < 8; ++s) wr[s] = W4g[wga[s] + ko];
    }
    __syncthreads();
#pragma unroll
    for (int ks = 0; ks < 4; ++ks) {
      int arow = wm * 16 + l15;
      int aoff = (arow * 256 + ks * 64 + gq * 16) ^ ((arow & 7) << 4);
      bf16x8 afr = *(const bf16x8*)(Xc + aoff);
#pragma unroll
      for (int nt = 0; nt < 2; ++nt) {
        int brow = wn * 32 + nt * 16 + l15;
        int boff = (brow * 256 + ks * 64 + gq * 16) ^ ((brow & 7) << 4);
        bf16x8 bfr = *(const bf16x8*)(W1c + boff);
        acc1[nt] = __builtin_amdgcn_mfma_f32_16x16x32_bf16(afr, bfr, acc1[nt], 0, 0, 0);
      }
    }
  }

  float b1v[2], g1v[2], be1v[2], b2v[2];
#pragma unroll
  for (int nt = 0; nt < 2; ++nt) {
    int c = wn * 32 + nt * 16 + l15;
    b1v[nt] = b1[c]; g1v[nt] = g1[c]; be1v[nt] = be1[c]; b2v[nt] = b2[c];
  }
  float yv[2][4], s_[4], q_[4];
#pragma unroll
  for (int i = 0; i < 4; ++i) {
    float s = 0.f, q = 0.f;
#pragma unroll
    for (int nt = 0; nt < 2; ++nt) {
      float y = acc1[nt][i] + b1v[nt];
      yv[nt][i] = y; s += y; q += y * y;
    }
    s_[i] = s; q_[i] = q;
  }
#pragma unroll
  for (int off = 1; off < 16; off <<= 1) {
#pragma unroll
    for (int i = 0; i < 4; ++i) {
      s_[i] += __shfl_xor(s_[i], off);
      q_[i] += __shfl_xor(q_[i], off);
    }
  }
  if (l15 == 0) {
#pragma unroll
    for (int i = 0; i < 4; ++i) {
      int row = wm * 16 + gq * 4 + i;
      float2 sv; sv.x = s_[i]; sv.y = q_[i];
      *(float2*)(lnb + (row * 2 + wn) * 2) = sv;
    }
  }
  __syncthreads();
#pragma unroll
  for (int i = 0; i < 4; ++i) {
    int row = wm * 16 + gq * 4 + i;
    float2 e0 = *(float2*)(lnb + (row * 2 + 0) * 2);
    float2 e1 = *(float2*)(lnb + (row * 2 + 1) * 2);
    float m = (e0.x + e1.x) * (1.0f / 64.0f);
    float var = (e0.y + e1.y) * (1.0f / 64.0f) - m * m;
    float rstd = rsqrtf(var + 1e-5f);
#pragma unroll
    for (int nt = 0; nt < 2; ++nt) {
      float h = (yv[nt][i] - m) * rstd * g1v[nt] + be1v[nt];
      h = fmaxf(h, 0.0f);
      int col = wn * 32 + nt * 16 + l15;
      int off2 = (row * 128 + col * 2) ^ ((row & 7) << 4);
      *(unsigned short*)(Hl + off2) = f2bf(h);
    }
  }
  __syncthreads();

  f32x4 acc2[2];
#pragma unroll
  for (int nt = 0; nt < 2; ++nt) { f32x4 z = {0.f,0.f,0.f,0.f}; acc2[nt] = z; }
#pragma unroll
  for (int ks = 0; ks < 2; ++ks) {
    int arow = wm * 16 + l15;
    int aoff = (arow * 128 + ks * 64 + gq * 16) ^ ((arow & 7) << 4);
    bf16x8 afr = *(const bf16x8*)(Hl + aoff);
#pragma unroll
    for (int nt = 0; nt < 2; ++nt) {
      int brow = wn * 32 + nt * 16 + l15;
      int boff = (brow * 128 + ks * 64 + gq * 16) ^ ((brow & 7) << 4);
      bf16x8 bfr = *(const bf16x8*)(W2l + boff);
      acc2[nt] = __builtin_amdgcn_mfma_f32_16x16x32_bf16(afr, bfr, acc2[nt], 0, 0, 0);
    }
  }
  float cs[2];
#pragma unroll
  for (int nt = 0; nt < 2; ++nt) {
    float s = 0.f;
#pragma unroll
    for (int i = 0; i < 4; ++i) s += fmaxf(acc2[nt][i] + b2v[nt], 0.0f);
    cs[nt] = s;
  }
#pragma unroll
  for (int nt = 0; nt < 2; ++nt) {
    cs[nt] += __shfl_xor(cs[nt], 16);
    cs[nt] += __shfl_xor(cs[nt], 32);
  }
  if (lane < 16) {
#pragma unroll
    for (int nt = 0; nt < 2; ++nt)
      cp[wm * 64 + wn * 32 + nt * 16 + lane] = cs[nt];
  }
  __syncthreads();
  if (tid < 64) c_part[blockIdx.x * 64 + tid] = cp[tid] + cp[64 + tid];
}

// ---------------------------------------------------------------------------
// Kernel 2: reduce c partials + head MLP. 1 block x 256 threads. (unchanged)
// ---------------------------------------------------------------------------
__global__ __launch_bounds__(256) void k_head(
    const float* __restrict__ c_part,
    const float* __restrict__ H1, const float* __restrict__ hb1,
    const float* __restrict__ g2, const float* __restrict__ be2,
    const float* __restrict__ H2, const float* __restrict__ hb2,
    float* __restrict__ u2out)
{
  __shared__ float part[256];
  __shared__ float clds[64];
  __shared__ float u1lds[128];
  __shared__ float red[8];
  int tid = threadIdx.x;
  {
    int col = tid & 63, g = tid >> 6;
    float s0 = 0.f, s1 = 0.f, s2 = 0.f, s3 = 0.f;
    int b0 = g * 64;
    for (int b = 0; b < 64; b += 4) {
      s0 += c_part[(b0 + b + 0) * 64 + col];
      s1 += c_part[(b0 + b + 1) * 64 + col];
      s2 += c_part[(b0 + b + 2) * 64 + col];
      s3 += c_part[(b0 + b + 3) * 64 + col];
    }
    part[tid] = (s0 + s1) + (s2 + s3);
  }
  __syncthreads();
  if (tid < 64)
    clds[tid] = (part[tid] + part[64 + tid] + part[128 + tid] + part[192 + tid]) * (1.0f / 8192.0f);
  __syncthreads();
  float acc = 0.f;
  if (tid < 128) {
    float a0 = 0.f, a1 = 0.f, a2 = 0.f, a3 = 0.f;
    for (int k = 0; k < 64; k += 4) {
      a0 += clds[k + 0] * H1[tid * 64 + k + 0];
      a1 += clds[k + 1] * H1[tid * 64 + k + 1];
      a2 += clds[k + 2] * H1[tid * 64 + k + 2];
      a3 += clds[k + 3] * H1[tid * 64 + k + 3];
    }
    acc = hb1[tid] + ((a0 + a1) + (a2 + a3));
  }
  float s = acc, q = acc * acc;
#pragma unroll
  for (int off = 1; off < 64; off <<= 1) { s += __shfl_xor(s, off); q += __shfl_xor(q, off); }
  int wv = tid >> 6;
  if ((tid & 63) == 0) { red[wv * 2] = s; red[wv * 2 + 1] = q; }
  __syncthreads();
  float S = red[0] + red[2], Q = red[1] + red[3];
  float m = S * (1.0f / 128.0f);
  float var = Q * (1.0f / 128.0f) - m * m;
  float rstd = rsqrtf(var + 1e-5f);
  if (tid < 128)
    u1lds[tid] = fmaxf((acc - m) * rstd * g2[tid] + be2[tid], 0.0f);
  __syncthreads();
  if (tid < 128) {
    float c0 = 0.f, c1 = 0.f, c2 = 0.f, c3 = 0.f;
    for (int k = 0; k < 128; k += 4) {
      c0 += u1lds[k + 0] * H2[tid * 128 + k + 0];
      c1 += u1lds[k + 1] * H2[tid * 128 + k + 1];
      c2 += u1lds[k + 2] * H2[tid * 128 + k + 2];
      c3 += u1lds[k + 3] * H2[tid * 128 + k + 3];
    }
    u2out[tid] = fmaxf(hb2[tid] + ((c0 + c1) + (c2 + c3)), 0.0f);
  }
}

// ---------------------------------------------------------------------------
// Kernel 3: params = u2 @ H3^T + hb3, routed to Bfrag / sb / ll / tw.
// Bfrag (u16 idx): kt*16384 + col*32 + (kgq ^ ((col>>1)&3))*8 + j
//   col = t*7+n (0..447), kt = d>>5, kgq = (d>>3)&3, j = d&7.
// s(col) = (col>>1)&3 gives 2/bank within every 16-lane phase on the
// consumer's ds_read_b128 (round-9 swizzle (col&3) was a 4-way conflict).
// ---------------------------------------------------------------------------
__global__ __launch_bounds__(256) void k_params(
    const float* __restrict__ H3, const float* __restrict__ hb3,
    const float* __restrict__ u2,
    unsigned short* __restrict__ Bfrag, float* __restrict__ sb,
    float* __restrict__ ll, float* __restrict__ tw)
{
  __shared__ float u2l[128];
  int tid = threadIdx.x;
  if (tid < 128) u2l[tid] = u2[tid];
  __syncthreads();
  int row = blockIdx.x * 64 + (tid >> 2);
  int sub = tid & 3;
  float acc = 0.0f;
  const float4* H4 = (const float4*)H3;
#pragma unroll
  for (int j = 0; j < 8; ++j) {
    int f = j * 4 + sub;
    float4 v = H4[row * 32 + f];
    acc += v.x * u2l[f * 4] + v.y * u2l[f * 4 + 1] + v.z * u2l[f * 4 + 2] + v.w * u2l[f * 4 + 3];
  }
  acc += __shfl_xor(acc, 1);
  acc += __shfl_xor(acc, 2);
  if (sub == 0) {
    float val = acc + hb3[row];
    if (row >= 230848) {
      tw[row - 230848] = val;
    } else {
      int t = row / PPTC;
      int r = row - t * PPTC;
      if (r < 3584) {
        int n = r >> 9, d = r & 511;
        int col = t * 7 + n;
        int kt = d >> 5, kgq = (d >> 3) & 3, j = d & 7;
        Bfrag[kt * 16384 + col * 32 + (kgq ^ ((col >> 1) & 3)) * 8 + j] = f2bf(val);
      } else if (r < 3591) {
        sb[t * 7 + (r - 3584)] = val;
      } else {
        ll[t * 16 + (r - 3591)] = val;
      }
    }
  }
}

// ---------------------------------------------------------------------------
// Kernel 4: main inference. 256 blocks x 512 thr (8 waves), BM=128, BN=448,
// BK=32, 16 K-tiles. Round-10 changes (LDS-throughput attack):
//  - A stored BF16 in LDS (halves A reads; cvt moved out of compute phase):
//    X reg-staged T14-style (global->reg, cvt_pk, ds_write_b64), dbuf 2x8KB.
//  - Phase-uniform swizzle s=( >>1)&3 on A and B granules: conflict-free.
//  - ONE barrier per K-iter: COMPUTE -> vmcnt(4) -> cvt+write X(t+1) ->
//    lgkmcnt(0) -> barrier -> load X(t+2), issue gl_lds B(t+3) (ring-3).
//    vmcnt counted, never 0 until the tail.
// ---------------------------------------------------------------------------
__global__ __launch_bounds__(512) void k_test(
    const float* __restrict__ Xt, const unsigned short* __restrict__ Bfrag,
    const float* __restrict__ sb, const float* __restrict__ ll,
    const float* __restrict__ tw, float* __restrict__ out)
{
  // Bb ring 3x32768 = 98304 ; Xb 2x8192 -> 114688 ; qlds 4096 -> 118784 ;
  // sbl 1792 -> 120576 ; outl 1024 -> 121600
  __shared__ __align__(16) char smem[121600];
  char* Pl = smem;                           // tree-phase alias (32 KB)
  char* Xb0 = smem + 98304;
  char* Xb1 = smem + 106496;
  float* qlds = (float*)(smem + 114688);
  float* sbl  = (float*)(smem + 118784);
  float* outl = (float*)(smem + 120576);

  const int tid = threadIdx.x;
  const int lane = tid & 63;
  const int wv = tid >> 6;
  const int l15 = lane & 15;
  const int gq = lane >> 4;
  const int wm = wv >> 2;
  const int wn = wv & 3;
  const int bm0 = blockIdx.x * 128;

  const float4* X4 = (const float4*)Xt;
  const char* Bf = (const char*)Bfrag;

  // ---- scalar prologue FIRST (its global loads drain before counted loads)
  if (tid < 448) sbl[tid] = sb[tid];
  if (tid < 64) {
    int t = tid;
    float x = tw[t];
    float m = x;
#pragma unroll
    for (int off = 1; off < 64; off <<= 1) m = fmaxf(m, __shfl_xor(m, off));
    float e = __expf(x - m);
    float s = e;
#pragma unroll
    for (int off = 1; off < 64; off <<= 1) s += __shfl_xor(s, off);
    float w = e / s;
#pragma unroll
    for (int l = 0; l < 8; ++l) {
      float a = ll[t * 16 + l * 2], b = ll[t * 16 + l * 2 + 1];
      float mm = fmaxf(a, b);
      float e0 = __expf(a - mm), e1 = __expf(b - mm);
      float inv = 2.0f * w / (e0 + e1);
      qlds[t * 16 + l * 2] = e0 * inv;
      qlds[t * 16 + l * 2 + 1] = e1 * inv;
    }
  }

  // ---- X staging addresses: thread t -> row r = t>>3 (and r+64), q = t&7.
  // 8 consecutive lanes = one 128B line (coalesced).
  const int xr_ = tid >> 3;           // 0..63
  const int xq_ = tid & 7;
  const int xsrc0 = (bm0 + xr_) * 128 + xq_;          // + kt*8 (float4 idx)
  const int xsrc1 = (bm0 + xr_ + 64) * 128 + xq_;
  // LDS write offset: granule g16 = q>>1 at position g16 ^ ((r>>1)&3), half q&1
  const int xwo0 = xr_ * 64 + (((xq_ >> 1) ^ ((xr_ >> 1) & 3)) << 4) + (xq_ & 1) * 8;
  // row+64 has same swizzle ((r+64)>>1)&3 == (r>>1)&3  -> +4096

  // ---- frag-read offsets (bf16 A now: ONE b128 per mt) ----
  int aoffs[4];
#pragma unroll
  for (int mt = 0; mt < 4; ++mt) {
    int row = wm * 64 + mt * 16 + l15;
    aoffs[mt] = row * 64 + ((gq ^ ((row >> 1) & 3)) << 4);
  }
  int boffs[7];
#pragma unroll
  for (int nt = 0; nt < 7; ++nt) {
    int col = wn * 112 + nt * 16 + l15;
    boffs[nt] = col * 64 + ((gq ^ ((col >> 1) & 3)) << 4);
  }

  f32x4 acc[4][7];
#pragma unroll
  for (int mt = 0; mt < 4; ++mt)
#pragma unroll
    for (int nt = 0; nt < 7; ++nt) { f32x4 z = {0.f,0.f,0.f,0.f}; acc[mt][nt] = z; }

#define LOADX(kt, a_, b_) do { \
    a_ = X4[xsrc0 + (kt) * 8]; b_ = X4[xsrc1 + (kt) * 8]; } while (0)
#define WRITEX(Xb, a_, b_) do { \
    *(uint2*)((Xb) + xwo0) = cvtpk2(a_); \
    *(uint2*)((Xb) + xwo0 + 4096) = cvtpk2(b_); } while (0)
#define ISSUEB(bb, kt) do { \
    const char* bt_ = Bf + (kt) * 32768; \
    gl_lds16(bt_ + tid * 16,          (bb) + tid * 16); \
    gl_lds16(bt_ + tid * 16 + 8192,   (bb) + tid * 16 + 8192); \
    gl_lds16(bt_ + tid * 16 + 16384,  (bb) + tid * 16 + 16384); \
    gl_lds16(bt_ + tid * 16 + 24576,  (bb) + tid * 16 + 24576); } while (0)
#define COMPUTE(Xb, Bb) do { \
    bf16x8 abf[4]; \
    _Pragma("unroll") \
    for (int mt = 0; mt < 4; ++mt) abf[mt] = *(const bf16x8*)((Xb) + aoffs[mt]); \
    _Pragma("unroll") \
    for (int nt = 0; nt < 7; ++nt) { \
      bf16x8 bfr = *(const bf16x8*)((Bb) + boffs[nt]); \
      _Pragma("unroll") \
      for (int mt = 0; mt < 4; ++mt) \
        acc[mt][nt] = __builtin_amdgcn_mfma_f32_16x16x32_bf16(abf[mt], bfr, acc[mt][nt], 0, 0, 0); \
    } } while (0)
#define VMWAIT(n) do { \
    asm volatile("s_waitcnt vmcnt(" #n ")" ::: "memory"); \
    __builtin_amdgcn_sched_barrier(0); } while (0)
#define LGKM0_BAR() do { \
    asm volatile("s_waitcnt lgkmcnt(0)" ::: "memory"); \
    __builtin_amdgcn_s_barrier(); } while (0)

  char* bb0 = smem;            // tile t     (t % 3 == 0 at start)
  char* bb1 = smem + 32768;    // tile t+1
  char* bb2 = smem + 65536;    // tile t+2

  float4 xrA0, xrA1;   // even-parity X tile regs
  float4 xrB0, xrB1;   // odd-parity X tile regs

  // ---- counted-load prologue. Queue: [B0(4), X0(2), B1(4), X1(2), B2(4)]
  ISSUEB(bb0, 0);
  LOADX(0, xrA0, xrA1);
  __builtin_amdgcn_sched_barrier(0);
  ISSUEB(bb1, 1);
  LOADX(1, xrB0, xrB1);
  __builtin_amdgcn_sched_barrier(0);
  ISSUEB(bb2, 2);
  VMWAIT(10);                     // drains B0, X0 ; leaves [B1,X1,B2]
  WRITEX(Xb0, xrA0, xrA1);        // X(0) -> Xb0
  LGKM0_BAR();                    // (also covers qlds/sbl writes)

  // ---- main loop: pairs t = 2i, 2i+1 for t = 0..11 ----
#pragma unroll 1
  for (int i = 0; i < 6; ++i) {
    const int t = 2 * i;
    // even t
    COMPUTE(Xb0, bb0);
    VMWAIT(4);                    // X(t+1) regs ready (B(t+2) stays in flight)
    WRITEX(Xb1, xrB0, xrB1);      // X(t+1) -> Xb1
    LGKM0_BAR();
    LOADX(t + 2, xrA0, xrA1);
    __builtin_amdgcn_sched_barrier(0);
    ISSUEB(bb0, t + 3);
    // odd t+1
    COMPUTE(Xb1, bb1);
    VMWAIT(4);
    WRITEX(Xb0, xrA0, xrA1);      // X(t+2) -> Xb0
    LGKM0_BAR();
    LOADX(t + 3, xrB0, xrB1);
    __builtin_amdgcn_sched_barrier(0);
    ISSUEB(bb1, t + 4);
    // rotate ring by 2
    char* tmp = bb0; bb0 = bb2; bb2 = bb1; bb1 = tmp;
  }
  // t = 12 (even; buffers back at start: bb0=tile12, bb1=13, bb2=14)
  COMPUTE(Xb0, bb0);
  VMWAIT(4);
  WRITEX(Xb1, xrB0, xrB1);        // X(13)
  LGKM0_BAR();
  LOADX(14, xrA0, xrA1);
  __builtin_amdgcn_sched_barrier(0);
  ISSUEB(bb0, 15);
  // t = 13
  COMPUTE(Xb1, bb1);
  VMWAIT(4);
  WRITEX(Xb0, xrA0, xrA1);        // X(14)
  LGKM0_BAR();
  LOADX(15, xrB0, xrB1);
  __builtin_amdgcn_sched_barrier(0);
  // t = 14
  COMPUTE(Xb0, bb2);
  VMWAIT(0);
  WRITEX(Xb1, xrB0, xrB1);        // X(15)
  LGKM0_BAR();
  // t = 15
  COMPUTE(Xb1, bb0);
  __syncthreads();                // full drain before tree phase aliases smem

  // q into registers (tree t = lane)
  float qreg[16];
  {
    const float4* q4 = (const float4*)qlds;
#pragma unroll
    for (int j = 0; j < 4; ++j) {
      float4 v = q4[lane * 4 + j];
      qreg[j * 4] = v.x; qreg[j * 4 + 1] = v.y; qreg[j * 4 + 2] = v.z; qreg[j * 4 + 3] = v.w;
    }
  }

  // ---- fused sigmoid + soft-tree + mixing, 4 passes of 32 rows ----
#pragma unroll
  for (int rg = 0; rg < 4; ++rg) {
    if (wm == (rg >> 1)) {
#pragma unroll
      for (int mtl = 0; mtl < 2; ++mtl) {
        const int mt = (rg & 1) * 2 + mtl;
#pragma unroll
        for (int nt = 0; nt < 7; ++nt) {
          int col = wn * 112 + nt * 16 + l15;
          float sbv = sbl[col];
          int t = col / 7;
          int j = col - t * 7;
          int slot2 = (t * 8 + j) * 2;
#pragma unroll
          for (int i = 0; i < 4; ++i) {
            int rl = mtl * 16 + gq * 4 + i;
            float p = sigmoidf_(acc[mt][nt][i] + sbv);
            *(_Float16*)(Pl + rl * 1024 + slot2) = (_Float16)p;
          }
        }
      }
    }
    __syncthreads();
#pragma unroll
    for (int k = 0; k < 4; ++k) {
      int rl = wv * 4 + k;
      h16x8 v = *(const h16x8*)(Pl + rl * 1024 + lane * 16);
      float p0 = (float)v[0], p1 = (float)v[1], p2 = (float)v[2];
      float p3 = (float)v[3], p4 = (float)v[4], p5 = (float)v[5], p6 = (float)v[6];
      float n0 = 1.f - p0, n1 = 1.f - p1, n2 = 1.f - p2;
      float a00 = n0 * n1, a01 = n0 * p1, a10 = p0 * n2, a11 = p0 * p2;
      float L0 = a00 * (1.f - p3), L1 = a00 * p3;
      float L2 = a01 * (1.f - p4), L3 = a01 * p4;
      float L4 = a10 * (1.f - p5), L5 = a10 * p5;
      float L6 = a11 * (1.f - p6), L7 = a11 * p6;
      float o0 = L0*qreg[0] + L1*qreg[2] + L2*qreg[4] + L3*qreg[6]
               + L4*qreg[8] + L5*qreg[10] + L6*qreg[12] + L7*qreg[14];
      float o1 = L0*qreg[1] + L1*qreg[3] + L2*qreg[5] + L3*qreg[7]
               + L4*qreg[9] + L5*qreg[11] + L6*qreg[13] + L7*qreg[15];
#pragma unroll
      for (int off = 1; off < 64; off <<= 1) {
        o0 += __shfl_xor(o0, off);
        o1 += __shfl_xor(o1, off);
      }
      if (lane == 0) {
        int gr = rg * 32 + rl;
        outl[gr * 2] = o0;
        outl[gr * 2 + 1] = o1;
      }
    }
    __syncthreads();
  }
  if (tid < 256) out[bm0 * 2 + tid] = outl[tid];
#undef LOADX
#undef WRITEX
#undef ISSUEB
#undef COMPUTE
#undef VMWAIT
#undef LGKM0_BAR
}

// ---------------------------------------------------------------------------
extern "C" void kernel_launch(void* const* d_in, const int* in_sizes, int n_in,
                              void* d_out, int out_size, void* d_ws, size_t ws_size,
                              hipStream_t stream)
{
  const float* Xtr = (const float*)d_in[0];
  const float* Xte = (const float*)d_in[1];
  const float* W1  = (const float*)d_in[3];
  const float* b1  = (const float*)d_in[4];
  const float* g1  = (const float*)d_in[5];
  const float* be1 = (const float*)d_in[6];
  const float* W2  = (const float*)d_in[7];
  const float* b2  = (const float*)d_in[8];
  const float* H1  = (const float*)d_in[9];
  const float* hb1 = (const float*)d_in[10];
  const float* g2  = (const float*)d_in[11];
  const float* be2 = (const float*)d_in[12];
  const float* H2  = (const float*)d_in[13];
  const float* hb2 = (const float*)d_in[14];
  const float* H3  = (const float*)d_in[15];
  const float* hb3 = (const float*)d_in[16];
  float* out = (float*)d_out;
  char* ws = (char*)d_ws;

  float* c_part = (float*)ws;                  // 256*64 f32 = 65536 B
  float* u2     = (float*)(ws + 65536);        // 128 f32
  float* sb     = (float*)(ws + 66048);        // 448 f32
  float* ll     = (float*)(ws + 67840);        // 1024 f32
  float* tw     = (float*)(ws + 71936);        // 64 f32
  unsigned short* Bfrag = (unsigned short*)(ws + 72192); // 16 tiles x 32 KB = 524288 B

  k_train<<<256, 256, 0, stream>>>(Xtr, W1, b1, g1, be1, W2, b2, c_part);
  k_head<<<1, 256, 0, stream>>>(c_part, H1, hb1, g2, be2, H2, hb2, u2);
  k_params<<<3608, 256, 0, stream>>>(H3, hb3, u2, Bfrag, sb, ll, tw);
  k_test<<<256, 512, 0, stream>>>(Xte, Bfrag, sb, ll, tw, out);
}